// Round 12
// baseline (301.979 us; speedup 1.0000x reference)
//
#include <hip/hip_runtime.h>
#include <math.h>

constexpr int NN = 20000;   // nodes
constexpr int NE = 320000;  // edges
constexpr int MROWS = 20224; // A1/A3 row padding
constexpr int MH = 20096;   // H1 rows (157 groups of 128)

typedef __bf16 bf16x8 __attribute__((ext_vector_type(8)));
typedef float f32x4 __attribute__((ext_vector_type(4)));

__device__ __forceinline__ unsigned short f2bf(float f) {
  unsigned int u = __float_as_uint(f);
  unsigned int r = (u + 0x7FFFu + ((u >> 16) & 1u)) >> 16;
  return (unsigned short)r;
}

// bijective XCD chunking (m204)
__device__ __forceinline__ int xcd_swizzle(int bid, int T) {
  int q = T >> 3, r = T & 7;
  int x = bid & 7, i = bid >> 3;
  return (x < r ? x * (q + 1) : r * (q + 1) + (x - r) * q) + i;
}

// ---------------- fast zero (replaces 43us hipMemsetAsync blit) ----------------
__global__ __launch_bounds__(256) void zero_kernel(int4* __restrict__ p, int n4) {
  int i = blockIdx.x * 256 + threadIdx.x;
  if (i < n4) p[i] = make_int4(0, 0, 0, 0);
}

// ---------------- degree count ----------------
__global__ void deg_count_kernel(const int* __restrict__ src, const int* __restrict__ dst,
                                 int* __restrict__ degs, int* __restrict__ degd, int nE) {
  int e = blockIdx.x * blockDim.x + threadIdx.x;
  if (e < nE) {
    atomicAdd(degs + src[e], 1);
    atomicAdd(degd + dst[e], 1);
  }
}

__global__ void norm_kernel(const int* __restrict__ degs, const int* __restrict__ degd,
                            float* __restrict__ ns, float* __restrict__ nd, int n) {
  int i = blockIdx.x * blockDim.x + threadIdx.x;
  if (i < n) {
    ns[i] = rsqrtf(fmaxf((float)degs[i], 1.0f));
    nd[i] = rsqrtf(fmaxf((float)degd[i], 1.0f));
  }
}

// ---------------- single-block exclusive scan -> rowptr ----------------
__global__ __launch_bounds__(1024) void scan_kernel(const int* __restrict__ deg,
                                                    int* __restrict__ rowptr, int n) {
  constexpr int T = 1024;
  const int ITEMS = (n + T - 1) / T;
  __shared__ int sums[T];
  int t = threadIdx.x;
  int base = t * ITEMS;
  int s = 0;
  for (int i = 0; i < ITEMS; ++i) {
    int idx = base + i;
    if (idx < n) s += deg[idx];
  }
  sums[t] = s;
  __syncthreads();
  for (int off = 1; off < T; off <<= 1) {
    int v = (t >= off) ? sums[t - off] : 0;
    __syncthreads();
    sums[t] += v;
    __syncthreads();
  }
  int ex = (t == 0) ? 0 : sums[t - 1];
  for (int i = 0; i < ITEMS; ++i) {
    int idx = base + i;
    if (idx < n) {
      rowptr[idx] = ex;
      ex += deg[idx];
    }
  }
  if (t == 0) rowptr[n] = sums[T - 1];
}

// ---------------- CSR fill ----------------
__global__ void csr_fill_kernel(const int* __restrict__ src, const int* __restrict__ dst,
                                const int* __restrict__ rowptr, int* __restrict__ cursor,
                                int* __restrict__ col, int nE) {
  int e = blockIdx.x * blockDim.x + threadIdx.x;
  if (e < nE) {
    int d = dst[e];
    int p = atomicAdd(cursor + d, 1);
    col[rowptr[d] + p] = src[e];
  }
}

// ---------------- weight convert: W[K][N] f32 -> Wt[Npad][Kpad] bf16 (zero pad) -------
__global__ void wt_convert_kernel(const float* __restrict__ W, unsigned short* __restrict__ Wt,
                                  int K, int N, int Kpad) {
  int k = blockIdx.x * 256 + threadIdx.x;
  int n = blockIdx.y;
  if (k >= Kpad) return;
  float v = (n < N && k < K) ? W[(size_t)k * N + n] : 0.f;
  Wt[(size_t)n * Kpad + k] = f2bf(v);
}

// ---------------- xb = bf16(x * ns[row]) pre-pass (8 elems/thread) ----------------
__global__ __launch_bounds__(256) void scale_cvt_kernel(
    const float* __restrict__ x, const float* __restrict__ ns,
    unsigned short* __restrict__ xb) {
  int t = blockIdx.x * 256 + threadIdx.x;  // one 8-elem chunk of a 256-wide row
  if (t >= NN * 32) return;
  int node = t >> 5;
  float sc = ns[node];
  float4 v1 = reinterpret_cast<const float4*>(x)[t * 2];
  float4 v2 = reinterpret_cast<const float4*>(x)[t * 2 + 1];
  uint4 o;
  o.x = f2bf(v1.x * sc) | ((unsigned)f2bf(v1.y * sc) << 16);
  o.y = f2bf(v1.z * sc) | ((unsigned)f2bf(v1.w * sc) << 16);
  o.z = f2bf(v2.x * sc) | ((unsigned)f2bf(v2.y * sc) << 16);
  o.w = f2bf(v2.z * sc) | ((unsigned)f2bf(v2.w * sc) << 16);
  reinterpret_cast<uint4*>(xb)[t] = o;
}

// ---------------- bf16 CSR gather: out[i] = SUM in[col[e]] (rows pre-scaled) --------
// 16 B/lane (8 bf16); LPN = F/8 lanes per node.
// EPI==0: bf16 sum -> out.
// EPI==1: v = sum*sDst+bias; bf16(v*snext[node]) -> out AND sigmoid(v) -> out2 (f32).
// EPI==2: v = sum*sDst+bias; sigmoid(v) -> out2 only.
template <int F, int EPI>
__global__ __launch_bounds__(256) void gatherb_kernel(
    const unsigned short* __restrict__ in, const int* __restrict__ rowptr,
    const int* __restrict__ col, const float* __restrict__ sDst,
    const float* __restrict__ bias, const float* __restrict__ snext,
    unsigned short* __restrict__ out, float* __restrict__ out2, int n) {
  constexpr int LPN = F / 8;
  constexpr int NPB = 256 / LPN;
  const int tid = threadIdx.x;
  const int node = blockIdx.x * NPB + tid / LPN;
  const int j = tid % LPN;
  if (node >= n) return;
  const int e0 = rowptr[node], e1 = rowptr[node + 1];
  float a[8] = {0.f, 0.f, 0.f, 0.f, 0.f, 0.f, 0.f, 0.f};
  for (int e = e0; e < e1; ++e) {
    int c = col[e];
    uint4 u = *reinterpret_cast<const uint4*>(in + (size_t)c * F + j * 8);
    a[0] += __uint_as_float(u.x << 16);
    a[1] += __uint_as_float(u.x & 0xffff0000u);
    a[2] += __uint_as_float(u.y << 16);
    a[3] += __uint_as_float(u.y & 0xffff0000u);
    a[4] += __uint_as_float(u.z << 16);
    a[5] += __uint_as_float(u.z & 0xffff0000u);
    a[6] += __uint_as_float(u.w << 16);
    a[7] += __uint_as_float(u.w & 0xffff0000u);
  }
  if (EPI == 0) {
    uint4 o;
    o.x = f2bf(a[0]) | ((unsigned)f2bf(a[1]) << 16);
    o.y = f2bf(a[2]) | ((unsigned)f2bf(a[3]) << 16);
    o.z = f2bf(a[4]) | ((unsigned)f2bf(a[5]) << 16);
    o.w = f2bf(a[6]) | ((unsigned)f2bf(a[7]) << 16);
    *reinterpret_cast<uint4*>(out + (size_t)node * F + j * 8) = o;
    return;
  }
  const float sd = sDst[node];
  float v[8];
#pragma unroll
  for (int k = 0; k < 8; ++k) v[k] = a[k] * sd + bias[j * 8 + k];
  if (EPI == 1) {
    float sn = snext[node];
    uint4 o;
    o.x = f2bf(v[0] * sn) | ((unsigned)f2bf(v[1] * sn) << 16);
    o.y = f2bf(v[2] * sn) | ((unsigned)f2bf(v[3] * sn) << 16);
    o.z = f2bf(v[4] * sn) | ((unsigned)f2bf(v[5] * sn) << 16);
    o.w = f2bf(v[6] * sn) | ((unsigned)f2bf(v[7] * sn) << 16);
    *reinterpret_cast<uint4*>(out + (size_t)node * F + j * 8) = o;
  }
  float4 s1, s2;
  s1.x = 1.0f / (1.0f + expf(-v[0]));
  s1.y = 1.0f / (1.0f + expf(-v[1]));
  s1.z = 1.0f / (1.0f + expf(-v[2]));
  s1.w = 1.0f / (1.0f + expf(-v[3]));
  s2.x = 1.0f / (1.0f + expf(-v[4]));
  s2.y = 1.0f / (1.0f + expf(-v[5]));
  s2.z = 1.0f / (1.0f + expf(-v[6]));
  s2.w = 1.0f / (1.0f + expf(-v[7]));
  *reinterpret_cast<float4*>(out2 + (size_t)node * F + j * 8) = s1;
  *reinterpret_cast<float4*>(out2 + (size_t)node * F + j * 8 + 4) = s2;
}

// ================= gemm8s: small-K GEMM (K = KT*32, KT<=8) — r10-proven ===========
template <int KT, int RELU>
__global__ __launch_bounds__(256) void gemm8s_kernel(
    const unsigned short* __restrict__ A, const unsigned short* __restrict__ Bt,
    unsigned short* __restrict__ C, int M, int Nreal, int NTn,
    const float* __restrict__ rowscale, const float* __restrict__ bias) {
  constexpr int K = KT * 32;
  constexpr int CPR = KT * 4;            // 16B chunks per LDS row
  constexpr int ROWB = CPR * 16;
  constexpr int TC = 64 * CPR;           // total chunks
  __shared__ __align__(16) char lds[64 * ROWB];

  const int sw = xcd_swizzle(blockIdx.x, gridDim.x);
  const int mg = sw / NTn, nt = sw - mg * NTn;  // n-fastest within XCD chunk
  const int tid = threadIdx.x;
  const int l = tid & 63, w = tid >> 6;
  const int lrow = l & 15, k16 = l >> 4;
  const int m0 = mg * 128 + w * 32, n0 = nt * 64;

  // ---- stage B[64][K] -> LDS (linear dest, inverse-swizzled source) ----
#pragma unroll
  for (int i = 0; i < TC / 256; ++i) {
    int c = i * 256 + tid;
    int row = c / CPR, lch = c % CPR;
    int gch = (lch & ~7) | ((lch & 7) ^ (row & 7));
    const unsigned short* gp = Bt + (size_t)(n0 + row) * K + gch * 8;
    __builtin_amdgcn_global_load_lds(
        (const __attribute__((address_space(1))) void*)gp,
        (__attribute__((address_space(3))) void*)(lds + (i * 256 + w * 64) * 16), 16, 0, 0);
  }

  // ---- issue ALL A-frags (independent of LDS) ----
  bf16x8 af[KT][2];
#pragma unroll
  for (int t = 0; t < KT; ++t)
#pragma unroll
    for (int mi = 0; mi < 2; ++mi)
      af[t][mi] = *reinterpret_cast<const bf16x8*>(
          A + (size_t)(m0 + mi * 16 + lrow) * K + t * 32 + k16 * 8);

  __syncthreads();  // single barrier: drains staging (and A-frags)

  // ---- pure LDS + MFMA burst ----
  f32x4 acc[2][4] = {};
#pragma unroll
  for (int t = 0; t < KT; ++t) {
    bf16x8 bf[4];
#pragma unroll
    for (int ni = 0; ni < 4; ++ni) {
      int row = ni * 16 + lrow;
      int ch = t * 4 + k16;
      int sc = (ch & ~7) | ((ch & 7) ^ (row & 7));
      bf[ni] = *reinterpret_cast<const bf16x8*>(lds + row * ROWB + sc * 16);
    }
#pragma unroll
    for (int mi = 0; mi < 2; ++mi)
#pragma unroll
      for (int ni = 0; ni < 4; ++ni)
        acc[mi][ni] = __builtin_amdgcn_mfma_f32_16x16x32_bf16(af[t][mi], bf[ni], acc[mi][ni], 0, 0, 0);
  }

  // ---- epilogue ----
#pragma unroll
  for (int mi = 0; mi < 2; ++mi) {
#pragma unroll
    for (int q = 0; q < 4; ++q) {
      int r = m0 + mi * 16 + k16 * 4 + q;
      if (r >= M) continue;
      float rs = rowscale[r];
#pragma unroll
      for (int ni = 0; ni < 4; ++ni) {
        int c = n0 + ni * 16 + lrow;
        if (c >= Nreal) continue;
        float v = acc[mi][ni][q] * rs + bias[c];
        if (RELU) v = fmaxf(v, 0.f);
        C[(size_t)r * Nreal + c] = f2bf(v);
      }
    }
  }
}

// ================= gemm8l: K=800 GEMM, B-tile staged in 2 LDS phases — r10-proven ==
template <int OUT_BF>
__global__ __launch_bounds__(256) void gemm8l_kernel(
    const unsigned short* __restrict__ A, const unsigned short* __restrict__ Bt,
    void* __restrict__ C, int M, int N, int NTn,
    const float* __restrict__ rowscale) {
  constexpr int K = 800, KPAD = 832;
  constexpr int CPR = 52;               // chunks per row per phase
  constexpr int ROWB = CPR * 16;
  __shared__ __align__(16) char lds[64 * ROWB];  // 52 KB

  const int sw = xcd_swizzle(blockIdx.x, gridDim.x);
  const int mg = sw / NTn, nt = sw - mg * NTn;
  const int tid = threadIdx.x;
  const int l = tid & 63, w = tid >> 6;
  const int lrow = l & 15, k16 = l >> 4;
  const int m0 = mg * 128 + w * 32, n0 = nt * 64;

  auto stage = [&](int phase) {
#pragma unroll
    for (int i = 0; i < 13; ++i) {  // 64*52/256
      int c = i * 256 + tid;
      int row = c / CPR, lch = c % CPR;
      int gch = phase * CPR + ((lch & ~3) | ((lch & 3) ^ (row & 3)));
      const unsigned short* gp = Bt + (size_t)(n0 + row) * KPAD + gch * 8;
      __builtin_amdgcn_global_load_lds(
          (const __attribute__((address_space(1))) void*)gp,
          (__attribute__((address_space(3))) void*)(lds + (i * 256 + w * 64) * 16), 16, 0, 0);
    }
  };

  f32x4 acc[2][4] = {};

  auto compute = [&](int t0, int t1, int phase) {
#pragma unroll 13
    for (int t = t0; t < t1; ++t) {
      bf16x8 a[2];
#pragma unroll
      for (int mi = 0; mi < 2; ++mi)
        a[mi] = *reinterpret_cast<const bf16x8*>(
            A + (size_t)(m0 + mi * 16 + lrow) * K + t * 32 + k16 * 8);
      bf16x8 bf[4];
#pragma unroll
      for (int ni = 0; ni < 4; ++ni) {
        int row = ni * 16 + lrow;
        int ch = t * 4 + k16 - phase * CPR;
        int sc = (ch & ~3) | ((ch & 3) ^ (row & 3));
        bf[ni] = *reinterpret_cast<const bf16x8*>(lds + row * ROWB + sc * 16);
      }
#pragma unroll
      for (int mi = 0; mi < 2; ++mi)
#pragma unroll
        for (int ni = 0; ni < 4; ++ni)
          acc[mi][ni] = __builtin_amdgcn_mfma_f32_16x16x32_bf16(a[mi], bf[ni], acc[mi][ni], 0, 0, 0);
    }
  };

  stage(0);
  __syncthreads();
  compute(0, 13, 0);      // chunks 0..51
  __syncthreads();        // all waves done with phase-0 LDS
  stage(1);
  __syncthreads();
  compute(13, 25, 1);     // chunks 52..99 (local 0..47)

#pragma unroll
  for (int mi = 0; mi < 2; ++mi) {
#pragma unroll
    for (int q = 0; q < 4; ++q) {
      int r = m0 + mi * 16 + k16 * 4 + q;
      if (r >= M) continue;
      float rs = rowscale[r];
#pragma unroll
      for (int ni = 0; ni < 4; ++ni) {
        int c = n0 + ni * 16 + lrow;
        float v = acc[mi][ni][q] * rs;
        if (OUT_BF) ((unsigned short*)C)[(size_t)r * N + c] = f2bf(v);
        else ((float*)C)[(size_t)r * N + c] = v;
      }
    }
  }
}

extern "C" void kernel_launch(void* const* d_in, const int* in_sizes, int n_in,
                              void* d_out, int out_size, void* d_ws, size_t ws_size,
                              hipStream_t stream) {
  const float* x  = (const float*)d_in[0];
  const int* src  = (const int*)d_in[1];
  const int* dst  = (const int*)d_in[2];
  const float* W1 = (const float*)d_in[3];
  const float* b1 = (const float*)d_in[4];
  const float* W2 = (const float*)d_in[5];
  const float* b2 = (const float*)d_in[6];
  const float* W3 = (const float*)d_in[7];
  const float* b3 = (const float*)d_in[8];
  const float* W4 = (const float*)d_in[9];
  const float* b4 = (const float*)d_in[10];

  float* out_enc = (float*)d_out;                  // [NN,128]
  float* out_dec = out_enc + (size_t)NN * 128;     // [NN,256]

  // ---- workspace layout (~82 MB) ----
  float* ns = (float*)d_ws;                        // [NN]
  float* nd = ns + NN;                             // [NN]
  unsigned short* xb  = (unsigned short*)(nd + NN);  // [NN*256]  bf16(x*ns)
  unsigned short* T2b = xb + (size_t)NN * 256;     // [NN*128] bf16 (gemm8l-L2 out)
  unsigned short* h2  = T2b + (size_t)NN * 128;    // [NN*128] bf16 (h2 * ns, L3 gather src)
  unsigned short* A1  = h2 + (size_t)NN * 128;     // [MROWS*256]
  unsigned short* A3  = A1 + (size_t)MROWS * 256;  // [MROWS*128]
  unsigned short* G4  = A3 + (size_t)MROWS * 128;  // [NN*256] bf16 (gemm8l-L4 out)
  unsigned short* H1  = G4 + (size_t)NN * 256;     // [MH*800] bf16 (gemm8s out)
  unsigned short* W1t = H1 + (size_t)MH * 800;     // [832*256]
  unsigned short* W2t = W1t + 832 * 256;           // [128*832]
  unsigned short* W3t = W2t + 128 * 832;           // [832*128]
  unsigned short* W4t = W3t + 832 * 128;           // [256*832]
  int* degs   = (int*)(W4t + 256 * 832);           // [NN]
  int* degd   = degs + NN;                         // [NN]
  int* cursor = degd + NN;                         // [NN]
  int* rowptr = cursor + NN;                       // [NN+1]
  int* col    = rowptr + NN + 1;                   // [NE]

  // ---- CSR build + norms (zero via kernel: hipMemsetAsync blit cost 43us!) ----
  zero_kernel<<<(3 * NN / 4 + 255) / 256, 256, 0, stream>>>((int4*)degs, 3 * NN / 4);
  deg_count_kernel<<<(NE + 255) / 256, 256, 0, stream>>>(src, dst, degs, degd, NE);
  norm_kernel<<<(NN + 255) / 256, 256, 0, stream>>>(degs, degd, ns, nd, NN);
  scan_kernel<<<1, 1024, 0, stream>>>(degd, rowptr, NN);
  csr_fill_kernel<<<(NE + 255) / 256, 256, 0, stream>>>(src, dst, rowptr, cursor, col, NE);

  // ---- weight conversion: Wt[Npad][Kpad] bf16 ----
  wt_convert_kernel<<<dim3(1, 832), 256, 0, stream>>>(W1, W1t, 256, 800, 256);
  wt_convert_kernel<<<dim3(4, 128), 256, 0, stream>>>(W2, W2t, 800, 128, 832);
  wt_convert_kernel<<<dim3(1, 832), 256, 0, stream>>>(W3, W3t, 128, 800, 128);
  wt_convert_kernel<<<dim3(4, 256), 256, 0, stream>>>(W4, W4t, 800, 256, 832);

  // grids
  const int GS = 157 * 13;   // gemm8s L1/L3 (Npad 832)
  const int GL2 = 157 * 2;   // gemm8l L2 (N=128)
  const int GL4 = 157 * 4;   // gemm8l L4 (N=256)

  // ---- L1: xb = bf16(x*ns); gather -> A1; gemm8s (K=256 -> 800) relu -> H1 ----
  scale_cvt_kernel<<<(NN * 32 + 255) / 256, 256, 0, stream>>>(x, ns, xb);
  gatherb_kernel<256, 0><<<(NN + 7) / 8, 256, 0, stream>>>(
      xb, rowptr, col, nullptr, nullptr, nullptr, A1, nullptr, NN);
  gemm8s_kernel<8, 1><<<GS, 256, 0, stream>>>(A1, W1t, H1, NN, 800, 13, nd, b1);

  // ---- L2: gemm8l (800 -> 128)*ns -> bf16 T2b; gather -> h2s=bf16(h2*ns) + sigmoid ----
  gemm8l_kernel<1><<<GL2, 256, 0, stream>>>(H1, W2t, T2b, NN, 128, 2, ns);
  gatherb_kernel<128, 1><<<(NN + 15) / 16, 256, 0, stream>>>(
      T2b, rowptr, col, nd, b2, ns, h2, out_enc, NN);

  // ---- L3: gather(h2s) -> A3; gemm8s (K=128 -> 800) relu -> H1 ----
  gatherb_kernel<128, 0><<<(NN + 15) / 16, 256, 0, stream>>>(
      h2, rowptr, col, nullptr, nullptr, nullptr, A3, nullptr, NN);
  gemm8s_kernel<4, 1><<<GS, 256, 0, stream>>>(A3, W3t, H1, NN, 800, 13, nd, b3);

  // ---- L4: gemm8l (800 -> 256)*ns -> bf16 G4; gather -> sigmoid(out_dec) ----
  gemm8l_kernel<1><<<GL4, 256, 0, stream>>>(H1, W4t, G4, NN, 256, 4, ns);
  gatherb_kernel<256, 2><<<(NN + 7) / 8, 256, 0, stream>>>(
      G4, rowptr, col, nd, b4, nullptr, nullptr, out_dec, NN);
}